// Round 3
// baseline (342.654 us; speedup 1.0000x reference)
//
#include <hip/hip_runtime.h>
#include <hip/hip_bf16.h>

// ssAttention fused kernel for MI355X (gfx950).
// Inputs fp32, OUTPUT fp32 (reference is an all-fp32 jnp pipeline).
// Internal compute: bf16 MFMA (16x16x32), fp32 accumulate; 2% relative gate.
// Decomposition: each pair position p=(a,b) owns a 16x128 slice (16 samples).
// One workgroup (4 waves) processes positions in a grid-stride loop:
//   LN -> Q,K,V,G proj (weights register-resident) -> per-head 16x16 attention
//   over samples -> gate -> out proj -> fp32 store.

typedef short bf16x8 __attribute__((ext_vector_type(8)));
typedef float f32x4 __attribute__((ext_vector_type(4)));

#define MFMA16x32(A, B, C) __builtin_amdgcn_mfma_f32_16x16x32_bf16((A), (B), (C), 0, 0, 0)

__device__ __forceinline__ unsigned short f2bf(float f) {
    unsigned int u = __float_as_uint(f);
    u += 0x7fffu + ((u >> 16) & 1u);   // RTNE
    return (unsigned short)(u >> 16);
}

static constexpr int  DD     = 128;
static constexpr int  NPOS   = 128 * 128;            // 16384 pair positions
static constexpr long ZSTR   = (long)NPOS * DD;      // sample stride in elements
static constexpr int  ZN_STR = 136;  // padded stride (ushort) for 16x128 bf16 LDS bufs
static constexpr int  SB_STR = 56;   // padded stride (ushort) for 16x32 bf16 LDS bufs
static constexpr int  OB_STR = 132;  // padded stride (float) for fp32 out staging

__launch_bounds__(256, 2)
__global__ void ssattn_fused(const float* __restrict__ z,
                             const float* __restrict__ ln_w,
                             const float* __restrict__ ln_b,
                             const float* __restrict__ Wq,
                             const float* __restrict__ Wk,
                             const float* __restrict__ Wv,
                             const float* __restrict__ Wg,
                             const float* __restrict__ bg,
                             const float* __restrict__ Wo,
                             const float* __restrict__ bo,
                             float* __restrict__ out)
{
    __shared__ __align__(16) unsigned short zn_s[16 * ZN_STR];    // zn (bf16), A-readable
    __shared__ __align__(16) unsigned short ob_s[16 * ZN_STR];    // gated O (bf16), A-readable
    __shared__ __align__(16) float outb_s[16 * OB_STR];           // out staging (fp32)
    __shared__ __align__(16) unsigned short qb_s[4][16 * SB_STR]; // per-wave Q (then P), K=32 pad
    __shared__ __align__(16) unsigned short kq_s[4][16 * SB_STR]; // per-wave K
    __shared__ __align__(16) unsigned short vb_s[4][16 * SB_STR]; // per-wave V^T
    __shared__ float lnw_s[DD];
    __shared__ float lnb_s[DD];

    const int tid  = threadIdx.x;
    const int wid  = tid >> 6;     // wave 0..3 -> heads {2w, 2w+1}
    const int lane = tid & 63;
    const int quad = lane >> 4;
    const int lm   = lane & 15;
    const int r16  = tid >> 4;     // row 0..15 for LN / store phases
    const int s16  = tid & 15;

    // ---- one-time setup: LN params to LDS, zero K=32 pad scratch ----
    if (tid < DD) { lnw_s[tid] = ln_w[tid]; lnb_s[tid] = ln_b[tid]; }
    for (int i = tid; i < 16 * SB_STR; i += 256) {
        qb_s[0][i] = 0; qb_s[1][i] = 0; qb_s[2][i] = 0; qb_s[3][i] = 0;
        kq_s[0][i] = 0; kq_s[1][i] = 0; kq_s[2][i] = 0; kq_s[3][i] = 0;
        vb_s[0][i] = 0; vb_s[1][i] = 0; vb_s[2][i] = 0; vb_s[3][i] = 0;
    }

    // ---- register-resident weights (fp32 -> bf16): B-frag B[k=kb*32+quad*8+j][n=col] ----
    bf16x8 wq_r[2][4], wk_r[2][4], wv_r[2][4], wg_r[2][4], wo_r[2][4];
    float bg_r[2], bo_r[2];
#pragma unroll
    for (int hl = 0; hl < 2; ++hl) {
        const int col = (wid * 2 + hl) * 16 + lm;
        bg_r[hl] = bg[col];
        bo_r[hl] = bo[col];
#pragma unroll
        for (int kb = 0; kb < 4; ++kb) {
            const int kbase = kb * 32 + quad * 8;
            bf16x8 a, b, c, d, e;
#pragma unroll
            for (int j = 0; j < 8; ++j) {
                const int k = kbase + j;
                a[j] = (short)f2bf(Wq[k * DD + col]);
                b[j] = (short)f2bf(Wk[k * DD + col]);
                c[j] = (short)f2bf(Wv[k * DD + col]);
                d[j] = (short)f2bf(Wg[k * DD + col]);
                e[j] = (short)f2bf(Wo[k * DD + col]);
            }
            wq_r[hl][kb] = a; wk_r[hl][kb] = b; wv_r[hl][kb] = c;
            wg_r[hl][kb] = d; wo_r[hl][kb] = e;
        }
    }
    __syncthreads();

    unsigned short* const qb = qb_s[wid];
    unsigned short* const kq = kq_s[wid];
    unsigned short* const vb = vb_s[wid];

    for (int p = blockIdx.x; p < NPOS; p += gridDim.x) {
        // ---- Phase A: load 16 z-rows (fp32), LayerNorm, store zn (bf16) ----
        {
            const float* zp = z + (long)r16 * ZSTR + (long)p * DD + s16 * 8;
            const float4 ra = *(const float4*)zp;
            const float4 rb = *(const float4*)(zp + 4);
            float x[8] = {ra.x, ra.y, ra.z, ra.w, rb.x, rb.y, rb.z, rb.w};
            float s = 0.f, ss = 0.f;
#pragma unroll
            for (int j = 0; j < 8; ++j) { s += x[j]; ss += x[j] * x[j]; }
#pragma unroll
            for (int m = 1; m <= 8; m <<= 1) {
                s  += __shfl_xor(s,  m, 16);
                ss += __shfl_xor(ss, m, 16);
            }
            const float mu = s * (1.f / 128.f);
            const float rs = rsqrtf(ss * (1.f / 128.f) - mu * mu + 1e-5f);
            unsigned int pk[4];
#pragma unroll
            for (int jj = 0; jj < 4; ++jj) {
                const int c0 = s16 * 8 + jj * 2;
                const unsigned short lo = f2bf((x[jj * 2]     - mu) * rs * lnw_s[c0]     + lnb_s[c0]);
                const unsigned short hi = f2bf((x[jj * 2 + 1] - mu) * rs * lnw_s[c0 + 1] + lnb_s[c0 + 1]);
                pk[jj] = (unsigned)lo | ((unsigned)hi << 16);
            }
            uint4 st; st.x = pk[0]; st.y = pk[1]; st.z = pk[2]; st.w = pk[3];
            *(uint4*)&zn_s[r16 * ZN_STR + s16 * 8] = st;
        }
        __syncthreads();

        // ---- Phase B: projections (MFMA) + per-head attention ----
        bf16x8 af[4];  // A-frags of zn (A[m=lm][k=kb*32+quad*8+j])
#pragma unroll
        for (int kb = 0; kb < 4; ++kb)
            af[kb] = *(const bf16x8*)&zn_s[lm * ZN_STR + kb * 32 + quad * 8];

#pragma unroll
        for (int hl = 0; hl < 2; ++hl) {
            f32x4 aq = {0,0,0,0}, ak = {0,0,0,0}, av = {0,0,0,0}, ag = {0,0,0,0};
#pragma unroll
            for (int kb = 0; kb < 4; ++kb) {
                aq = MFMA16x32(af[kb], wq_r[hl][kb], aq);
                ak = MFMA16x32(af[kb], wk_r[hl][kb], ak);
                av = MFMA16x32(af[kb], wv_r[hl][kb], av);
                ag = MFMA16x32(af[kb], wg_r[hl][kb], ag);
            }
            // C/D layout: row = quad*4+r, col = lm.  Scale 1/sqrt(16) folded into Q.
#pragma unroll
            for (int r = 0; r < 4; ++r) {
                const int row = quad * 4 + r;
                qb[row * SB_STR + lm] = f2bf(aq[r] * 0.25f);  // Q[i][c]
                kq[row * SB_STR + lm] = f2bf(ak[r]);          // K[j][c]
                vb[lm * SB_STR + row] = f2bf(av[r]);          // V^T[c][j]
            }
            float gv[4];
#pragma unroll
            for (int r = 0; r < 4; ++r)
                gv[r] = 1.f / (1.f + __expf(-(ag[r] + bg_r[hl])));

            // att = (Q/4) @ K^T. K-dim (=C=16) zero-padded to 32.
            const bf16x8 aqf = *(const bf16x8*)&qb[lm * SB_STR + quad * 8];
            const bf16x8 bkf = *(const bf16x8*)&kq[lm * SB_STR + quad * 8];
            const f32x4 z4 = {0,0,0,0};
            f32x4 att = MFMA16x32(aqf, bkf, z4);

            // softmax over j (= C/D col = lm across the 16 lanes of this quad)
            f32x4 pr;
#pragma unroll
            for (int r = 0; r < 4; ++r) {
                const float a = att[r];
                float mx = a;
#pragma unroll
                for (int m = 1; m <= 8; m <<= 1) mx = fmaxf(mx, __shfl_xor(mx, m, 16));
                const float ex = __expf(a - mx);
                float sm = ex;
#pragma unroll
                for (int m = 1; m <= 8; m <<= 1) sm += __shfl_xor(sm, m, 16);
                pr[r] = ex / sm;
            }
            // P overwrites Q buffer (Q frags already consumed; same-wave DS ops in-order)
#pragma unroll
            for (int r = 0; r < 4; ++r)
                qb[(quad * 4 + r) * SB_STR + lm] = f2bf(pr[r]);

            // O = P @ V : A-frag of P, B-frag from V^T rows (contiguous k=j)
            const bf16x8 apf = *(const bf16x8*)&qb[lm * SB_STR + quad * 8];
            const bf16x8 bvf = *(const bf16x8*)&vb[lm * SB_STR + quad * 8];
            f32x4 oc = MFMA16x32(apf, bvf, z4);

            const int hcol = (wid * 2 + hl) * 16 + lm;
#pragma unroll
            for (int r = 0; r < 4; ++r)
                ob_s[(quad * 4 + r) * ZN_STR + hcol] = f2bf(oc[r] * gv[r]);
        }
        __syncthreads();

        // ---- Phase C: out = O @ Wo + bo (fp32 staging) ----
        bf16x8 of[4];
#pragma unroll
        for (int kb = 0; kb < 4; ++kb)
            of[kb] = *(const bf16x8*)&ob_s[lm * ZN_STR + kb * 32 + quad * 8];
#pragma unroll
        for (int hl = 0; hl < 2; ++hl) {
            f32x4 acc = {0,0,0,0};
#pragma unroll
            for (int kb = 0; kb < 4; ++kb)
                acc = MFMA16x32(of[kb], wo_r[hl][kb], acc);
            const int col = (wid * 2 + hl) * 16 + lm;
#pragma unroll
            for (int r = 0; r < 4; ++r)
                outb_s[(quad * 4 + r) * OB_STR + col] = acc[r] + bo_r[hl];
        }
        __syncthreads();

        // ---- Phase D: fp32 store, 32 B/lane (512 B contiguous per row) ----
        {
            float* op = out + (long)r16 * ZSTR + (long)p * DD + s16 * 8;
            const float* sp = &outb_s[r16 * OB_STR + s16 * 8];
            float4 v0 = *(const float4*)(sp);
            float4 v1 = *(const float4*)(sp + 4);
            *(float4*)(op)     = v0;
            *(float4*)(op + 4) = v1;
        }
        __syncthreads();
    }
}

extern "C" void kernel_launch(void* const* d_in, const int* in_sizes, int n_in,
                              void* d_out, int out_size, void* d_ws, size_t ws_size,
                              hipStream_t stream) {
    (void)in_sizes; (void)n_in; (void)out_size; (void)d_ws; (void)ws_size;
    // 512 blocks = 2 blocks/CU; 16384/512 = 32 positions per block (uniform).
    ssattn_fused<<<dim3(512), dim3(256), 0, stream>>>(
        (const float*)d_in[0],  // z
        (const float*)d_in[1],  // ln_w
        (const float*)d_in[2],  // ln_b
        (const float*)d_in[3],  // Wq
        (const float*)d_in[4],  // Wk
        (const float*)d_in[5],  // Wv
        (const float*)d_in[6],  // Wg
        (const float*)d_in[7],  // bg
        (const float*)d_in[8],  // Wo
        (const float*)d_in[9],  // bo
        (float*)d_out);
}